// Round 4
// baseline (517.000 us; speedup 1.0000x reference)
//
#include <hip/hip_runtime.h>
#include <hip/hip_cooperative_groups.h>
#include <math.h>

namespace cg = cooperative_groups;

#define S 128
#define H 64
#define NSEG 8
#define SEGCAP 131072   // ceil(1024 blocks / 8 segs) * 1024 samples

// ---------------------------------------------------------------------------
// Exact-geometry occupancy mask (identical op sequence to the round-0 kernel;
// _rn intrinsics forbid fma contraction so floor() cells bit-match numpy).
// ---------------------------------------------------------------------------
__device__ __forceinline__ bool sample_mask(
    float ox, float oy, float oz, float dx, float dy, float dz,
    float nr, float step, int s, const float* __restrict__ density)
{
    const float z  = __fadd_rn(nr, __fmul_rn((float)s, step));
    const float px = __fadd_rn(ox, __fmul_rn(z, dx));
    const float py = __fadd_rn(oy, __fmul_rn(z, dy));
    const float pz = __fadd_rn(oz, __fmul_rn(z, dz));
    const float gx = floorf(__fmul_rn(__fdiv_rn(__fsub_rn(px, -1.25f), 2.5f), 64.0f));
    const float gy = floorf(__fmul_rn(__fdiv_rn(__fsub_rn(py, -1.55f), 2.5f), 64.0f));
    const float gz = floorf(__fmul_rn(__fdiv_rn(__fsub_rn(pz, -1.25f), 2.5f), 64.0f));
    const int ix = (int)gx, iy = (int)gy, iz = (int)gz;
    const bool inb = (ix >= 0) && (ix < 64) && (iy >= 0) && (iy < 64) &&
                     (iz >= 0) && (iz < 64);
    const int cx = min(max(ix, 0), 63);
    const int cy = min(max(iy, 0), 63);
    const int cz = min(max(iz, 0), 63);
    const float dval = density[(cx << 12) | (cy << 6) | cz];
    return inb && (dval > 0.5f);
}

// ---------------------------------------------------------------------------
// Fused cooperative kernel: mask+compact -> grid.sync -> MLP -> grid.sync ->
// composite. 1024 blocks x 256 threads, launch_bounds(256,4) guarantees
// 4 blocks/CU co-residency (128-reg cap) so grid.sync cannot deadlock.
// ---------------------------------------------------------------------------
__global__ __launch_bounds__(256, 4)
void fused_kernel(const float* __restrict__ rays_o, const float* __restrict__ rays_d,
                  const float* __restrict__ nearv, const float* __restrict__ farv,
                  const float* __restrict__ jitter, const float* __restrict__ density,
                  const float* __restrict__ W1, const float* __restrict__ b1,
                  const float* __restrict__ W2, const float* __restrict__ b2,
                  const float* __restrict__ Wsig, const float* __restrict__ bsig,
                  const float* __restrict__ Wrgb, const float* __restrict__ brgb,
                  int* __restrict__ counters,        // [NSEG], pre-zeroed by memset node
                  unsigned int* __restrict__ list,   // [NSEG*SEGCAP]
                  float* __restrict__ alpha,         // [NS]
                  float* __restrict__ rgbws,         // [NS*3]
                  float* __restrict__ out, int N, int NS)
{
    cg::grid_group grid = cg::this_grid();
    __shared__ int s_wcnt[4];
    __shared__ int s_wbase[4];
    __shared__ int s_base;

    const int tid  = threadIdx.x;
    const int lane = tid & 63;
    const int wv   = tid >> 6;
    const int blk  = blockIdx.x;

    // ================= Phase A: mask + compaction =================
    // 4 consecutive samples per thread -> all in the same ray (4-aligned
    // chunks of a 128-sample ray), so ray data is loaded once per thread.
    const int gbase = blk * 1024 + tid * 4;
    unsigned int mybits = 0u;
    if (gbase < NS) {
        const int ray = gbase >> 7;
        const float ox = rays_o[ray * 3 + 0], oy = rays_o[ray * 3 + 1], oz = rays_o[ray * 3 + 2];
        const float dx = rays_d[ray * 3 + 0], dy = rays_d[ray * 3 + 1], dz = rays_d[ray * 3 + 2];
        const float nr = nearv[ray];
        const float step = __fdiv_rn(__fsub_rn(farv[ray], nr), 128.0f);
        const int s0 = gbase & (S - 1);
        #pragma unroll
        for (int j = 0; j < 4; ++j) {
            const bool m = sample_mask(ox, oy, oz, dx, dy, dz, nr, step, s0 + j, density);
            if (m) mybits |= (1u << j);
            else   alpha[gbase + j] = 0.0f;   // active ones written in phase B
        }
    }
    const int mycnt = __popc(mybits);
    // wave-inclusive scan of per-thread counts
    int inc = mycnt;
    #pragma unroll
    for (int off = 1; off < 64; off <<= 1) {
        const int u = __shfl_up(inc, off, 64);
        if (lane >= off) inc += u;
    }
    if (lane == 63) s_wcnt[wv] = inc;
    __syncthreads();
    if (tid == 0) {
        const int t0 = s_wcnt[0], t1 = s_wcnt[1], t2 = s_wcnt[2], t3 = s_wcnt[3];
        s_wbase[0] = 0; s_wbase[1] = t0; s_wbase[2] = t0 + t1; s_wbase[3] = t0 + t1 + t2;
        // 8 counters -> 8 parallel atomic chains of ~128 instead of 1024 serial
        s_base = atomicAdd(&counters[blk & (NSEG - 1)], t0 + t1 + t2 + t3);
    }
    __syncthreads();
    {
        int pos = (blk & (NSEG - 1)) * SEGCAP + s_base + s_wbase[wv] + (inc - mycnt);
        #pragma unroll
        for (int j = 0; j < 4; ++j) {
            if ((mybits >> j) & 1u) list[pos++] = (unsigned int)(gbase + j);
        }
    }

    __threadfence();
    grid.sync();

    // ================= Phase B: MLP over compacted samples =================
    // Weight reads are wave-uniform -> scalarized to s_load through the
    // constant cache; vector pipe does only FMAs. h2[64] lands in AGPRs.
    int pre[NSEG + 1];
    pre[0] = 0;
    #pragma unroll
    for (int s2 = 0; s2 < NSEG; ++s2) pre[s2 + 1] = pre[s2] + counters[s2];
    const int total = pre[NSEG];
    const int nth = gridDim.x * 256;

    for (int i = blk * 256 + tid; i < total; i += nth) {
        int seg = 0;
        #pragma unroll
        for (int s2 = 1; s2 < NSEG; ++s2) if (i >= pre[s2]) seg = s2;
        const unsigned int ga = list[seg * SEGCAP + (i - pre[seg])];

        const int r = (int)(ga >> 7);
        const int s = (int)(ga & (S - 1));
        const float nr = nearv[r];
        const float step = __fdiv_rn(__fsub_rn(farv[r], nr), 128.0f);
        const float zs = __fadd_rn(nr, __fmul_rn((float)s, step));
        const float zj = zs + jitter[ga] * step;
        const float qx = rays_o[r * 3 + 0] + zj * rays_d[r * 3 + 0];
        const float qy = rays_o[r * 3 + 1] + zj * rays_d[r * 3 + 1];
        const float qz = rays_o[r * 3 + 2] + zj * rays_d[r * 3 + 2];

        float h2[H];
        #pragma unroll
        for (int j = 0; j < H; ++j) h2[j] = b2[j];

        for (int k = 0; k < H; ++k) {
            const float h1k = fmaxf(
                fmaf(qx, W1[k], fmaf(qy, W1[H + k], fmaf(qz, W1[2 * H + k], b1[k]))), 0.0f);
            const float4* __restrict__ w2v = reinterpret_cast<const float4*>(W2 + (k << 6));
            #pragma unroll
            for (int j4 = 0; j4 < H / 4; ++j4) {
                const float4 w = w2v[j4];
                h2[4 * j4 + 0] = fmaf(h1k, w.x, h2[4 * j4 + 0]);
                h2[4 * j4 + 1] = fmaf(h1k, w.y, h2[4 * j4 + 1]);
                h2[4 * j4 + 2] = fmaf(h1k, w.z, h2[4 * j4 + 2]);
                h2[4 * j4 + 3] = fmaf(h1k, w.w, h2[4 * j4 + 3]);
            }
        }

        float sig = bsig[0], cr = brgb[0], cg2 = brgb[1], cb = brgb[2];
        #pragma unroll
        for (int j = 0; j < H; ++j) {
            const float v = fmaxf(h2[j], 0.0f);
            sig = fmaf(v, Wsig[j], sig);
            cr  = fmaf(v, Wrgb[j * 3 + 0], cr);
            cg2 = fmaf(v, Wrgb[j * 3 + 1], cg2);
            cb  = fmaf(v, Wrgb[j * 3 + 2], cb);
        }
        const float tau = fmaxf(sig, 0.0f) * step;
        alpha[ga] = 1.0f - expf(-tau);
        rgbws[ga * 3 + 0] = 1.0f / (1.0f + expf(-cr));
        rgbws[ga * 3 + 1] = 1.0f / (1.0f + expf(-cg2));
        rgbws[ga * 3 + 2] = 1.0f / (1.0f + expf(-cb));
    }

    __threadfence();
    grid.sync();

    // ================= Phase C: composite (1 ray per wave-iteration) =======
    const int gw = blk * 4 + wv;
    const int nwaves = gridDim.x * 4;
    for (int ray = gw; ray < N; ray += nwaves) {
        const int b0 = ray * S + 2 * lane;
        const float a0 = alpha[b0];
        const float a1 = alpha[b0 + 1];
        const float t0 = (1.0f - a0) + 1e-10f;
        const float t1 = (1.0f - a1) + 1e-10f;
        float v = t0 * t1;
        #pragma unroll
        for (int off = 1; off < 64; off <<= 1) {
            const float u = __shfl_up(v, off, 64);
            if (lane >= off) v *= u;
        }
        float excl = __shfl_up(v, 1, 64);
        if (lane == 0) excl = 1.0f;
        const float no_hit = __shfl(v, 63, 64);
        const float w0 = a0 * excl;
        const float w1 = a1 * (excl * t0);
        float cr = w0 * rgbws[b0 * 3 + 0] + w1 * rgbws[b0 * 3 + 3];
        float cg2 = w0 * rgbws[b0 * 3 + 1] + w1 * rgbws[b0 * 3 + 4];
        float cb = w0 * rgbws[b0 * 3 + 2] + w1 * rgbws[b0 * 3 + 5];
        #pragma unroll
        for (int off = 32; off >= 1; off >>= 1) {
            cr  += __shfl_xor(cr, off, 64);
            cg2 += __shfl_xor(cg2, off, 64);
            cb  += __shfl_xor(cb, off, 64);
        }
        if (lane == 0) {
            out[ray * 3 + 0] = cr + no_hit;
            out[ray * 3 + 1] = cg2 + no_hit;
            out[ray * 3 + 2] = cb + no_hit;
        }
    }
}

// ===========================================================================
// Multi-kernel fallback (round-3 path) — used if cooperative launch fails
// or sizes don't fit the fused kernel's assumptions.
// ===========================================================================
__global__ void zero_counter(int* c) { for (int i = 0; i < NSEG; ++i) c[i] = 0; }

__global__ __launch_bounds__(1024)
void mask_kernel(const float* __restrict__ rays_o, const float* __restrict__ rays_d,
                 const float* __restrict__ nearv, const float* __restrict__ farv,
                 const float* __restrict__ density,
                 unsigned int* __restrict__ list, int* __restrict__ counter,
                 float* __restrict__ alpha, int NS)
{
    __shared__ int s_wcnt[16];
    __shared__ int s_wbase[16];
    __shared__ int s_gbase;
    const int tid  = threadIdx.x;
    const int lane = tid & 63;
    const int wv   = tid >> 6;
    const int gid  = blockIdx.x * 1024 + tid;
    bool m = false;
    if (gid < NS) {
        const int ray = gid >> 7;
        const int s   = gid & (S - 1);
        const float ox = rays_o[ray * 3 + 0], oy = rays_o[ray * 3 + 1], oz = rays_o[ray * 3 + 2];
        const float dx = rays_d[ray * 3 + 0], dy = rays_d[ray * 3 + 1], dz = rays_d[ray * 3 + 2];
        const float nr = nearv[ray];
        const float step = __fdiv_rn(__fsub_rn(farv[ray], nr), 128.0f);
        m = sample_mask(ox, oy, oz, dx, dy, dz, nr, step, s, density);
        if (!m) alpha[gid] = 0.0f;
    }
    const unsigned long long bal = __ballot(m);
    const int before = __popcll(bal & ((1ull << lane) - 1ull));
    if (lane == 0) s_wcnt[wv] = __popcll(bal);
    __syncthreads();
    if (tid == 0) {
        int tot = 0;
        #pragma unroll
        for (int i = 0; i < 16; ++i) { s_wbase[i] = tot; tot += s_wcnt[i]; }
        s_gbase = atomicAdd(counter, tot);
    }
    __syncthreads();
    if (m) list[s_gbase + s_wbase[wv] + before] = (unsigned int)gid;
}

__global__ __launch_bounds__(256)
void mlp_kernel(const unsigned int* __restrict__ list, const int* __restrict__ counter,
                const float* __restrict__ rays_o, const float* __restrict__ rays_d,
                const float* __restrict__ nearv, const float* __restrict__ farv,
                const float* __restrict__ jitter,
                const float* __restrict__ W1, const float* __restrict__ b1,
                const float* __restrict__ W2, const float* __restrict__ b2,
                const float* __restrict__ Wsig, const float* __restrict__ bsig,
                const float* __restrict__ Wrgb, const float* __restrict__ brgb,
                float* __restrict__ alpha, float* __restrict__ rgbout)
{
    const int total = *counter;
    for (int i = blockIdx.x * 256 + threadIdx.x; i < total; i += gridDim.x * 256) {
        const unsigned int ga = list[i];
        const int r = (int)(ga >> 7);
        const int s = (int)(ga & (S - 1));
        const float nr = nearv[r];
        const float step = __fdiv_rn(__fsub_rn(farv[r], nr), 128.0f);
        const float zs = __fadd_rn(nr, __fmul_rn((float)s, step));
        const float zj = zs + jitter[ga] * step;
        const float qx = rays_o[r * 3 + 0] + zj * rays_d[r * 3 + 0];
        const float qy = rays_o[r * 3 + 1] + zj * rays_d[r * 3 + 1];
        const float qz = rays_o[r * 3 + 2] + zj * rays_d[r * 3 + 2];
        float h2[H];
        #pragma unroll
        for (int j = 0; j < H; ++j) h2[j] = b2[j];
        for (int k = 0; k < H; ++k) {
            const float h1k = fmaxf(
                fmaf(qx, W1[k], fmaf(qy, W1[H + k], fmaf(qz, W1[2 * H + k], b1[k]))), 0.0f);
            const float4* __restrict__ w2v = reinterpret_cast<const float4*>(W2 + (k << 6));
            #pragma unroll
            for (int j4 = 0; j4 < H / 4; ++j4) {
                const float4 w = w2v[j4];
                h2[4 * j4 + 0] = fmaf(h1k, w.x, h2[4 * j4 + 0]);
                h2[4 * j4 + 1] = fmaf(h1k, w.y, h2[4 * j4 + 1]);
                h2[4 * j4 + 2] = fmaf(h1k, w.z, h2[4 * j4 + 2]);
                h2[4 * j4 + 3] = fmaf(h1k, w.w, h2[4 * j4 + 3]);
            }
        }
        float sig = bsig[0], cr = brgb[0], cg = brgb[1], cb = brgb[2];
        #pragma unroll
        for (int j = 0; j < H; ++j) {
            const float v = fmaxf(h2[j], 0.0f);
            sig = fmaf(v, Wsig[j], sig);
            cr  = fmaf(v, Wrgb[j * 3 + 0], cr);
            cg  = fmaf(v, Wrgb[j * 3 + 1], cg);
            cb  = fmaf(v, Wrgb[j * 3 + 2], cb);
        }
        const float tau = fmaxf(sig, 0.0f) * step;
        alpha[ga] = 1.0f - expf(-tau);
        rgbout[ga * 3 + 0] = 1.0f / (1.0f + expf(-cr));
        rgbout[ga * 3 + 1] = 1.0f / (1.0f + expf(-cg));
        rgbout[ga * 3 + 2] = 1.0f / (1.0f + expf(-cb));
    }
}

__global__ __launch_bounds__(256)
void composite_kernel(const float* __restrict__ alpha, const float* __restrict__ rgb,
                      float* __restrict__ out, int N)
{
    const int lane = threadIdx.x & 63;
    const int ray = blockIdx.x * 4 + (threadIdx.x >> 6);
    if (ray >= N) return;
    const int b0 = ray * S + 2 * lane;
    const float a0 = alpha[b0];
    const float a1 = alpha[b0 + 1];
    const float t0 = (1.0f - a0) + 1e-10f;
    const float t1 = (1.0f - a1) + 1e-10f;
    float v = t0 * t1;
    #pragma unroll
    for (int off = 1; off < 64; off <<= 1) {
        const float u = __shfl_up(v, off, 64);
        if (lane >= off) v *= u;
    }
    float excl = __shfl_up(v, 1, 64);
    if (lane == 0) excl = 1.0f;
    const float no_hit = __shfl(v, 63, 64);
    const float w0 = a0 * excl;
    const float w1 = a1 * (excl * t0);
    float cr = w0 * rgb[b0 * 3 + 0] + w1 * rgb[b0 * 3 + 3];
    float cg = w0 * rgb[b0 * 3 + 1] + w1 * rgb[b0 * 3 + 4];
    float cb = w0 * rgb[b0 * 3 + 2] + w1 * rgb[b0 * 3 + 5];
    #pragma unroll
    for (int off = 32; off >= 1; off >>= 1) {
        cr += __shfl_xor(cr, off, 64);
        cg += __shfl_xor(cg, off, 64);
        cb += __shfl_xor(cb, off, 64);
    }
    if (lane == 0) {
        out[ray * 3 + 0] = cr + no_hit;
        out[ray * 3 + 1] = cg + no_hit;
        out[ray * 3 + 2] = cb + no_hit;
    }
}

extern "C" void kernel_launch(void* const* d_in, const int* in_sizes, int n_in,
                              void* d_out, int out_size, void* d_ws, size_t ws_size,
                              hipStream_t stream) {
    const float* rays_o  = (const float*)d_in[0];
    const float* rays_d  = (const float*)d_in[1];
    const float* nearv   = (const float*)d_in[2];
    const float* farv    = (const float*)d_in[3];
    const float* jitter  = (const float*)d_in[4];
    const float* density = (const float*)d_in[5];
    const float* W1      = (const float*)d_in[6];
    const float* b1      = (const float*)d_in[7];
    const float* W2      = (const float*)d_in[8];
    const float* b2      = (const float*)d_in[9];
    const float* Wsig    = (const float*)d_in[10];
    const float* bsig    = (const float*)d_in[11];
    const float* Wrgb    = (const float*)d_in[12];
    const float* brgb    = (const float*)d_in[13];
    float* out = (float*)d_out;

    int N = in_sizes[2];
    int NS = N * S;

    // ws layout: counters[NSEG] | list[NSEG*SEGCAP] | alpha[NS] | rgb[NS*3]
    char* ws = (char*)d_ws;
    int* counters     = (int*)ws;
    unsigned int* lst = (unsigned int*)(ws + 256);
    float* alpha      = (float*)(ws + 256 + (size_t)NSEG * SEGCAP * 4);
    float* rgbws      = (float*)(ws + 256 + (size_t)NSEG * SEGCAP * 4 + (size_t)NS * 4);
    const size_t need = 256 + (size_t)NSEG * SEGCAP * 4 + (size_t)NS * 16;

    const bool fits_fused = (ws_size >= need) && (NS <= 1024 * 1024);

    if (fits_fused) {
        hipMemsetAsync(counters, 0, NSEG * sizeof(int), stream);
        const int nblocks = 1024;
        void* args[] = {
            (void*)&rays_o, (void*)&rays_d, (void*)&nearv, (void*)&farv,
            (void*)&jitter, (void*)&density,
            (void*)&W1, (void*)&b1, (void*)&W2, (void*)&b2,
            (void*)&Wsig, (void*)&bsig, (void*)&Wrgb, (void*)&brgb,
            (void*)&counters, (void*)&lst, (void*)&alpha, (void*)&rgbws,
            (void*)&out, (void*)&N, (void*)&NS
        };
        hipError_t err = hipLaunchCooperativeKernel(
            (void*)fused_kernel, dim3(nblocks), dim3(256), args, 0, stream);
        if (err == hipSuccess) return;
        // fall through to multi-kernel path on failure
    }

    if (ws_size < need) return;   // cannot run — should not happen with harness ws

    zero_counter<<<dim3(1), dim3(1), 0, stream>>>(counters);
    mask_kernel<<<dim3((NS + 1023) / 1024), dim3(1024), 0, stream>>>(
        rays_o, rays_d, nearv, farv, density, lst, counters, alpha, NS);
    mlp_kernel<<<dim3(2048), dim3(256), 0, stream>>>(
        lst, counters, rays_o, rays_d, nearv, farv, jitter,
        W1, b1, W2, b2, Wsig, bsig, Wrgb, brgb, alpha, rgbws);
    composite_kernel<<<dim3((N + 3) / 4), dim3(256), 0, stream>>>(alpha, rgbws, out, N);
}

// Round 5
// 147.982 us; speedup vs baseline: 3.4937x; 3.4937x over previous
//
#include <hip/hip_runtime.h>
#include <math.h>

#define S 128
#define H 64
#define NSEG 8
#define SEGCAP 131072

// ---------------------------------------------------------------------------
// Exact-geometry occupancy mask (identical op sequence to the round-0 kernel;
// _rn intrinsics forbid fma contraction so floor() cells bit-match numpy).
// ---------------------------------------------------------------------------
__device__ __forceinline__ bool sample_mask(
    float ox, float oy, float oz, float dx, float dy, float dz,
    float nr, float step, int s, const float* __restrict__ density)
{
    const float z  = __fadd_rn(nr, __fmul_rn((float)s, step));
    const float px = __fadd_rn(ox, __fmul_rn(z, dx));
    const float py = __fadd_rn(oy, __fmul_rn(z, dy));
    const float pz = __fadd_rn(oz, __fmul_rn(z, dz));
    const float gx = floorf(__fmul_rn(__fdiv_rn(__fsub_rn(px, -1.25f), 2.5f), 64.0f));
    const float gy = floorf(__fmul_rn(__fdiv_rn(__fsub_rn(py, -1.55f), 2.5f), 64.0f));
    const float gz = floorf(__fmul_rn(__fdiv_rn(__fsub_rn(pz, -1.25f), 2.5f), 64.0f));
    const int ix = (int)gx, iy = (int)gy, iz = (int)gz;
    const bool inb = (ix >= 0) && (ix < 64) && (iy >= 0) && (iy < 64) &&
                     (iz >= 0) && (iz < 64);
    const int cx = min(max(ix, 0), 63);
    const int cy = min(max(iy, 0), 63);
    const int cz = min(max(iz, 0), 63);
    const float dval = density[(cx << 12) | (cy << 6) | cz];
    return inb && (dval > 0.5f);
}

// ---------------------------------------------------------------------------
// K1: mask + segmented compaction. 512 threads/block, 4 samples/thread
// (4-aligned chunk stays inside one 128-sample ray -> ray data loaded once,
// wave-uniform -> scalarized). Shuffle inclusive scan of per-thread counts,
// LDS scan of 8 wave totals, ONE atomicAdd per block into one of 8 segment
// counters (blk&7) -> 8 parallel chains of ~64 atomics instead of a single
// 1024-long serial chain (round-2 measured ~9 ns per same-line RMW).
// Compaction arithmetic identical to round-4 phase A (verified absmax 0.0).
// ---------------------------------------------------------------------------
__global__ __launch_bounds__(512)
void mask_kernel(const float* __restrict__ rays_o, const float* __restrict__ rays_d,
                 const float* __restrict__ nearv, const float* __restrict__ farv,
                 const float* __restrict__ density,
                 unsigned int* __restrict__ list, int* __restrict__ counters,
                 float* __restrict__ alpha, int NS)
{
    __shared__ int s_wcnt[8];
    __shared__ int s_wbase[8];
    __shared__ int s_base;

    const int tid  = threadIdx.x;
    const int lane = tid & 63;
    const int wv   = tid >> 6;
    const int blk  = blockIdx.x;
    const int gbase = blk * 2048 + tid * 4;

    unsigned int mybits = 0u;
    if (gbase < NS) {
        const int ray = gbase >> 7;   // wave-uniform? no — uniform per thread; loads scalarize per-wave where possible
        const float ox = rays_o[ray * 3 + 0], oy = rays_o[ray * 3 + 1], oz = rays_o[ray * 3 + 2];
        const float dx = rays_d[ray * 3 + 0], dy = rays_d[ray * 3 + 1], dz = rays_d[ray * 3 + 2];
        const float nr = nearv[ray];
        const float step = __fdiv_rn(__fsub_rn(farv[ray], nr), 128.0f);
        const int s0 = gbase & (S - 1);
        #pragma unroll
        for (int j = 0; j < 4; ++j) {
            const bool m = sample_mask(ox, oy, oz, dx, dy, dz, nr, step, s0 + j, density);
            if (m) mybits |= (1u << j);
            else   alpha[gbase + j] = 0.0f;   // active samples written by K2
        }
    }
    const int mycnt = __popc(mybits);
    int inc = mycnt;
    #pragma unroll
    for (int off = 1; off < 64; off <<= 1) {
        const int u = __shfl_up(inc, off, 64);
        if (lane >= off) inc += u;
    }
    if (lane == 63) s_wcnt[wv] = inc;
    __syncthreads();
    if (tid == 0) {
        int tot = 0;
        #pragma unroll
        for (int i = 0; i < 8; ++i) { s_wbase[i] = tot; tot += s_wcnt[i]; }
        s_base = atomicAdd(&counters[blk & (NSEG - 1)], tot);
    }
    __syncthreads();
    int pos = (blk & (NSEG - 1)) * SEGCAP + s_base + s_wbase[wv] + (inc - mycnt);
    #pragma unroll
    for (int j = 0; j < 4; ++j) {
        if ((mybits >> j) & 1u) list[pos++] = (unsigned int)(gbase + j);
    }
}

// ---------------------------------------------------------------------------
// K2: MLP over the 8 concatenated segments. One sample per thread (round-2
// showed 2/thread hits the VGPR cliff). Weight reads are wave-uniform ->
// scalarized to s_load through the scalar cache; vector pipe does only FMAs;
// h2[64] lands in the unified AGPR file (round-3: VGPR_Count=44).
// Launched with enough threads that nearly every thread does exactly one
// sample (round-3's 31% occupancy was ramp+tail, not a resource cap).
// ---------------------------------------------------------------------------
__global__ __launch_bounds__(256)
void mlp_kernel(const unsigned int* __restrict__ list, const int* __restrict__ counters,
                const float* __restrict__ rays_o, const float* __restrict__ rays_d,
                const float* __restrict__ nearv, const float* __restrict__ farv,
                const float* __restrict__ jitter,
                const float* __restrict__ W1, const float* __restrict__ b1,
                const float* __restrict__ W2, const float* __restrict__ b2,
                const float* __restrict__ Wsig, const float* __restrict__ bsig,
                const float* __restrict__ Wrgb, const float* __restrict__ brgb,
                float* __restrict__ alpha, float* __restrict__ rgbout)
{
    int pre[NSEG + 1];
    pre[0] = 0;
    #pragma unroll
    for (int s2 = 0; s2 < NSEG; ++s2) pre[s2 + 1] = pre[s2] + counters[s2];
    const int total = pre[NSEG];
    const int nth = gridDim.x * 256;

    for (int i = blockIdx.x * 256 + threadIdx.x; i < total; i += nth) {
        int seg = 0;
        #pragma unroll
        for (int s2 = 1; s2 < NSEG; ++s2) if (i >= pre[s2]) seg = s2;
        const unsigned int ga = list[seg * SEGCAP + (i - pre[seg])];

        const int r = (int)(ga >> 7);
        const int s = (int)(ga & (S - 1));
        const float nr = nearv[r];
        const float step = __fdiv_rn(__fsub_rn(farv[r], nr), 128.0f);
        const float zs = __fadd_rn(nr, __fmul_rn((float)s, step));
        const float zj = zs + jitter[ga] * step;
        const float qx = rays_o[r * 3 + 0] + zj * rays_d[r * 3 + 0];
        const float qy = rays_o[r * 3 + 1] + zj * rays_d[r * 3 + 1];
        const float qz = rays_o[r * 3 + 2] + zj * rays_d[r * 3 + 2];

        float h2[H];
        #pragma unroll
        for (int j = 0; j < H; ++j) h2[j] = b2[j];

        for (int k = 0; k < H; ++k) {
            const float h1k = fmaxf(
                fmaf(qx, W1[k], fmaf(qy, W1[H + k], fmaf(qz, W1[2 * H + k], b1[k]))), 0.0f);
            const float4* __restrict__ w2v = reinterpret_cast<const float4*>(W2 + (k << 6));
            #pragma unroll
            for (int j4 = 0; j4 < H / 4; ++j4) {
                const float4 w = w2v[j4];
                h2[4 * j4 + 0] = fmaf(h1k, w.x, h2[4 * j4 + 0]);
                h2[4 * j4 + 1] = fmaf(h1k, w.y, h2[4 * j4 + 1]);
                h2[4 * j4 + 2] = fmaf(h1k, w.z, h2[4 * j4 + 2]);
                h2[4 * j4 + 3] = fmaf(h1k, w.w, h2[4 * j4 + 3]);
            }
        }

        float sig = bsig[0], cr = brgb[0], cg = brgb[1], cb = brgb[2];
        #pragma unroll
        for (int j = 0; j < H; ++j) {
            const float v = fmaxf(h2[j], 0.0f);
            sig = fmaf(v, Wsig[j], sig);
            cr  = fmaf(v, Wrgb[j * 3 + 0], cr);
            cg  = fmaf(v, Wrgb[j * 3 + 1], cg);
            cb  = fmaf(v, Wrgb[j * 3 + 2], cb);
        }
        const float tau = fmaxf(sig, 0.0f) * step;
        alpha[ga] = 1.0f - expf(-tau);
        rgbout[ga * 3 + 0] = 1.0f / (1.0f + expf(-cr));
        rgbout[ga * 3 + 1] = 1.0f / (1.0f + expf(-cg));
        rgbout[ga * 3 + 2] = 1.0f / (1.0f + expf(-cb));
    }
}

// ---------------------------------------------------------------------------
// K3: wave-per-ray composite. 2 samples per lane, shuffle product scan for
// transmittance, shuffle reduce for color. Inactive samples have alpha==0 ->
// w==0 -> their (poison-filled) rgb contributes exactly 0.
// ---------------------------------------------------------------------------
__global__ __launch_bounds__(512)
void composite_kernel(const float* __restrict__ alpha, const float* __restrict__ rgb,
                      float* __restrict__ out, int N)
{
    const int lane = threadIdx.x & 63;
    const int ray = blockIdx.x * 8 + (threadIdx.x >> 6);
    if (ray >= N) return;
    const int b0 = ray * S + 2 * lane;
    const float a0 = alpha[b0];
    const float a1 = alpha[b0 + 1];
    const float t0 = (1.0f - a0) + 1e-10f;
    const float t1 = (1.0f - a1) + 1e-10f;
    float v = t0 * t1;
    #pragma unroll
    for (int off = 1; off < 64; off <<= 1) {
        const float u = __shfl_up(v, off, 64);
        if (lane >= off) v *= u;
    }
    float excl = __shfl_up(v, 1, 64);
    if (lane == 0) excl = 1.0f;
    const float no_hit = __shfl(v, 63, 64);
    const float w0 = a0 * excl;
    const float w1 = a1 * (excl * t0);
    float cr = w0 * rgb[b0 * 3 + 0] + w1 * rgb[b0 * 3 + 3];
    float cg = w0 * rgb[b0 * 3 + 1] + w1 * rgb[b0 * 3 + 4];
    float cb = w0 * rgb[b0 * 3 + 2] + w1 * rgb[b0 * 3 + 5];
    #pragma unroll
    for (int off = 32; off >= 1; off >>= 1) {
        cr += __shfl_xor(cr, off, 64);
        cg += __shfl_xor(cg, off, 64);
        cb += __shfl_xor(cb, off, 64);
    }
    if (lane == 0) {
        out[ray * 3 + 0] = cr + no_hit;
        out[ray * 3 + 1] = cg + no_hit;
        out[ray * 3 + 2] = cb + no_hit;
    }
}

extern "C" void kernel_launch(void* const* d_in, const int* in_sizes, int n_in,
                              void* d_out, int out_size, void* d_ws, size_t ws_size,
                              hipStream_t stream) {
    const float* rays_o  = (const float*)d_in[0];
    const float* rays_d  = (const float*)d_in[1];
    const float* nearv   = (const float*)d_in[2];
    const float* farv    = (const float*)d_in[3];
    const float* jitter  = (const float*)d_in[4];
    const float* density = (const float*)d_in[5];
    const float* W1      = (const float*)d_in[6];
    const float* b1      = (const float*)d_in[7];
    const float* W2      = (const float*)d_in[8];
    const float* b2      = (const float*)d_in[9];
    const float* Wsig    = (const float*)d_in[10];
    const float* bsig    = (const float*)d_in[11];
    const float* Wrgb    = (const float*)d_in[12];
    const float* brgb    = (const float*)d_in[13];
    float* out = (float*)d_out;

    const int N = in_sizes[2];
    const int NS = N * S;

    // ws layout: counters[NSEG] (256 B pad) | list[NSEG*SEGCAP] | alpha[NS] | rgb[NS*3]
    char* ws = (char*)d_ws;
    int* counters     = (int*)ws;
    unsigned int* lst = (unsigned int*)(ws + 256);
    float* alpha      = (float*)(ws + 256 + (size_t)NSEG * SEGCAP * 4);
    float* rgbws      = (float*)(ws + 256 + (size_t)NSEG * SEGCAP * 4 + (size_t)NS * 4);

    hipMemsetAsync(counters, 0, NSEG * sizeof(int), stream);

    // K1: 512 threads x 4 samples = 2048 samples/block
    mask_kernel<<<dim3((NS + 2047) / 2048), dim3(512), 0, stream>>>(
        rays_o, rays_d, nearv, farv, density, lst, counters, alpha, NS);

    // K2: 2048 blocks x 256 = 524288 threads >= worst-case active count
    mlp_kernel<<<dim3(2048), dim3(256), 0, stream>>>(
        lst, counters, rays_o, rays_d, nearv, farv, jitter,
        W1, b1, W2, b2, Wsig, bsig, Wrgb, brgb, alpha, rgbws);

    // K3: 8 rays/block
    composite_kernel<<<dim3((N + 7) / 8), dim3(512), 0, stream>>>(alpha, rgbws, out, N);
}